// Round 5
// baseline (367.581 us; speedup 1.0000x reference)
//
#include <hip/hip_runtime.h>
#include <hip/hip_bf16.h>
#include <stdint.h>

#define BDIM 32
#define SDIM 4096
#define SP1  4097
#define EDIM 256
#define FDIM 256
#define LDIM 50
#define TT   64
#define NTT  65    // tiles per batch row (tile 64 covers t=4096 only)
#define NCH  16    // chains per batch row; chain 15 has 5 tiles

typedef __attribute__((ext_vector_type(8))) short bf16x8v;
typedef __attribute__((ext_vector_type(4))) float f32x4;

__device__ __forceinline__ unsigned short f2bf(float f) {
    union { float f; uint32_t u; } v; v.f = f;
    uint32_t u = v.u;
    uint32_t r = (u + 0x7fffu + ((u >> 16) & 1u)) >> 16;
    return (unsigned short)r;
}

// tanh(x) = 1 - 2/(1+e^{2x}); v_rcp_f32 (~1ulp) is plenty vs bf16 storage noise.
__device__ __forceinline__ float tanh_fast(float x) {
    float e = __expf(2.0f * x);
    float r = __builtin_amdgcn_rcpf(e + 1.0f);
    return fmaf(-2.0f, r, 1.0f);
}

__device__ __forceinline__ uint32_t pack_bf2(float lo, float hi) {
    union { __hip_bfloat162 v; uint32_t u; } cv;
    cv.v = __halves2bfloat162(__float2bfloat16(lo), __float2bfloat16(hi));
    return cv.u;
}

__device__ __forceinline__ void load_lds16(const void* g, uint32_t* l) {
    __builtin_amdgcn_global_load_lds(
        (const __attribute__((address_space(1))) uint32_t*)g,
        (__attribute__((address_space(3))) uint32_t*)l, 16, 0, 0);
}

// ---- Prep A: Wb[f][kk] bf16 (kk=k*256+e), W2k[g][c][j] bf16, zero page ----
__global__ void prep_misc(const float* __restrict__ conv_w,
                          const float* __restrict__ U_w, const float* __restrict__ final_w,
                          unsigned short* __restrict__ Wb, unsigned short* __restrict__ W2k,
                          uint32_t* __restrict__ zp) {
    int o = blockIdx.x * 256 + threadIdx.x;          // grid 1024 -> o < 262144
    { int e = o & 255, k = (o >> 8) & 3, f = o >> 10;
      Wb[o] = f2bf(conv_w[f * 1024 + e * 4 + k]); }
    if (o < 32768) {
        int j = o & 7, c = (o >> 3) & 127, g = o >> 10;
        int k = g * 8 + j, l = c & 63;
        float v = 0.f;
        if (l < LDIM) v = (c < 64) ? U_w[l * FDIM + k] : final_w[l * FDIM + k];
        W2k[o] = f2bf(v);
    }
    if (o < 128) zp[o] = 0;
}

// ---- Prep B: embedding table fp32 -> bf16 ----
__global__ void prep_embb(const float* __restrict__ emb, unsigned short* __restrict__ embb) {
    size_t o = ((size_t)blockIdx.x * 256 + threadIdx.x) * 8;
    if (o >= (size_t)30522 * 256) return;
    float4 v0 = *(const float4*)(emb + o);
    float4 v1 = *(const float4*)(emb + o + 4);
    union { unsigned short u[8]; uint4 q; } pk;
    pk.u[0] = f2bf(v0.x); pk.u[1] = f2bf(v0.y); pk.u[2] = f2bf(v0.z); pk.u[3] = f2bf(v0.w);
    pk.u[4] = f2bf(v1.x); pk.u[5] = f2bf(v1.y); pk.u[6] = f2bf(v1.z); pk.u[7] = f2bf(v1.w);
    *(uint4*)(embb + o) = pk.q;
}

// ids for one tile: 34 two-row load_lds ops; nid[j] = -1 means zero row.
__device__ __forceinline__ void stage_ids(const int* __restrict__ ids, int b, int t0,
                                          int wid, int half, int (&nid)[9]) {
    #pragma unroll
    for (int j = 0; j < 9; ++j) {
        int m = wid + 4 * j;
        nid[j] = -1;
        if (m < 34) {
            int r = 2 * m + half;
            int p = t0 - 2 + r;
            if (r < 67 && (unsigned)p < SDIM) nid[j] = ids[b * SDIM + p];
        }
    }
}

__device__ __forceinline__ void stage_gather(const unsigned short* __restrict__ embb,
                                             const uint32_t* __restrict__ zp,
                                             int wid, int half, int q, const int (&nid)[9],
                                             uint32_t* buf) {
    #pragma unroll
    for (int j = 0; j < 9; ++j) {
        int m = wid + 4 * j;
        if (m >= 34) continue;                       // wave-uniform
        int r = 2 * m + half;
        const unsigned short* src = (nid[j] >= 0)
            ? embb + (size_t)nid[j] * EDIM + (((q * 16) ^ ((r & 7) << 4)) >> 1)
            : (const unsigned short*)zp + q * 8;
        load_lds16(src, &buf[2 * m * 128]);
    }
}

// ---- Fused pipelined kernel: chain of TT-tiles, double-buffered x-stage ----
__global__ __launch_bounds__(256, 2) void fused_kernel(
    const int* __restrict__ ids, const unsigned short* __restrict__ embb,
    const unsigned short* __restrict__ Wb, const float* __restrict__ conv_b,
    const unsigned short* __restrict__ W2k, const uint32_t* __restrict__ zp,
    float* __restrict__ part)
{
    __shared__ uint32_t xs[2][68 * 128];   // 2 x 34,816 B double-buffered x/H tile

    const int tid   = threadIdx.x;
    const int lane  = tid & 63;
    const int wid   = tid >> 6;            // 0..3
    const int b     = blockIdx.y;
    const int chain = blockIdx.x;
    const int tbeg  = chain * 4;
    const int ntl   = (chain == NCH - 1) ? 5 : 4;
    const int l15   = lane & 15;
    const int hi4   = lane >> 4;
    const int q     = lane & 31;
    const int half  = lane >> 5;
    const int wm    = wid & 1;             // conv filter half
    const int wn    = wid >> 1;            // conv position half

    const unsigned short* ap[8];
    #pragma unroll
    for (int a = 0; a < 8; ++a)
        ap[a] = Wb + (size_t)(wm * 128 + a * 16 + l15) * 1024 + hi4 * 8;
    const unsigned short* wp0 = W2k + (size_t)(hi4 * 128 + wid * 16 + l15) * 8;

    int nid[9];
    // prologue: stage tile 0, preload ids for tile 1
    stage_ids(ids, b, tbeg * TT, wid, half, nid);
    stage_gather(embb, zp, wid, half, q, nid, &xs[0][0]);
    if (ntl > 1) stage_ids(ids, b, (tbeg + 1) * TT, wid, half, nid);
    __syncthreads();

    #pragma unroll 1
    for (int i = 0; i < ntl; ++i) {
        const int cur = i & 1;
        const int t0  = (tbeg + i) * TT;
        const uint32_t* xcur = &xs[cur][0];

        // issue next tile's gathers into the free buffer (hidden under this tile)
        if (i + 1 < ntl) stage_gather(embb, zp, wid, half, q, nid, &xs[cur ^ 1][0]);
        // preload ids for tile i+2 (hidden under conv)
        if (i + 2 < ntl) stage_ids(ids, b, (tbeg + i + 2) * TT, wid, half, nid);

        // ---- Conv GEMM: wave = 128f (M) x 32t (N), K=1024 ----
        f32x4 acc[8][2];
        #pragma unroll
        for (int a = 0; a < 8; ++a) { acc[a][0] = (f32x4){0,0,0,0}; acc[a][1] = (f32x4){0,0,0,0}; }

        #pragma unroll 1
        for (int k = 0; k < 4; ++k) {
            uint32_t bb[2];
            #pragma unroll
            for (int n = 0; n < 2; ++n) {
                int r = wn * 32 + n * 16 + l15 + k;
                bb[n] = (uint32_t)(r * 512) ^ (uint32_t)(hi4 * 16) ^ (uint32_t)((r & 7) << 4);
            }
            #pragma unroll
            for (int es = 0; es < 8; ++es) {
                bf16x8v af[8], bfr[2];
                #pragma unroll
                for (int a = 0; a < 8; ++a)
                    af[a] = *(const bf16x8v*)(ap[a] + k * 256 + es * 32);   // imm offsets
                #pragma unroll
                for (int n = 0; n < 2; ++n)
                    bfr[n] = *(const bf16x8v*)((const char*)xcur + (bb[n] ^ (uint32_t)(es * 64)));
                #pragma unroll
                for (int a = 0; a < 8; ++a)
                    #pragma unroll
                    for (int n = 0; n < 2; ++n)
                        acc[a][n] = __builtin_amdgcn_mfma_f32_16x16x32_bf16(af[a], bfr[n], acc[a][n], 0, 0, 0);
            }
        }
        __syncthreads();   // all x-reads done (also drains in-flight gathers: already landed)

        // ---- tanh epilogue -> H rows 0..63 in same buffer, XOR-swizzled ----
        #pragma unroll
        for (int n = 0; n < 2; ++n) {
            int tl = wn * 32 + n * 16 + l15;
            uint32_t hb = (uint32_t)(tl * 512) ^ (uint32_t)(hi4 * 8)
                        ^ (uint32_t)(wm * 256) ^ (uint32_t)((tl & 7) << 4);
            #pragma unroll
            for (int a = 0; a < 8; ++a) {
                float4 cb = *(const float4*)(conv_b + wm * 128 + a * 16 + hi4 * 4);
                f32x4 d = acc[a][n];
                uint2 pk;
                pk.x = pack_bf2(tanh_fast(d[0] + cb.x), tanh_fast(d[1] + cb.y));
                pk.y = pack_bf2(tanh_fast(d[2] + cb.z), tanh_fast(d[3] + cb.w));
                *(uint2*)((char*)xcur + (hb ^ (uint32_t)(a * 32))) = pk;
            }
        }
        __syncthreads();

        // ---- P GEMM: 64 s-rows x 32 cols per wave (wid*16 scores, +64 t), K=256 ----
        f32x4 p2[4][2];
        #pragma unroll
        for (int m = 0; m < 4; ++m) { p2[m][0] = (f32x4){0,0,0,0}; p2[m][1] = (f32x4){0,0,0,0}; }
        uint32_t pb[4];
        #pragma unroll
        for (int m = 0; m < 4; ++m) {
            int sl = m * 16 + l15;
            pb[m] = (uint32_t)(sl * 512) ^ (uint32_t)(hi4 * 16) ^ (uint32_t)((sl & 7) << 4);
        }
        #pragma unroll
        for (int step = 0; step < 8; ++step) {
            bf16x8v ha[4], w2[2];
            #pragma unroll
            for (int m = 0; m < 4; ++m)
                ha[m] = *(const bf16x8v*)((const char*)xcur + (pb[m] ^ (uint32_t)(step * 64)));
            w2[0] = *(const bf16x8v*)(wp0 + step * 4096);
            w2[1] = *(const bf16x8v*)(wp0 + 512 + step * 4096);
            #pragma unroll
            for (int m = 0; m < 4; ++m) {
                p2[m][0] = __builtin_amdgcn_mfma_f32_16x16x32_bf16(ha[m], w2[0], p2[m][0], 0, 0, 0);
                p2[m][1] = __builtin_amdgcn_mfma_f32_16x16x32_bf16(ha[m], w2[1], p2[m][1], 0, 0, 0);
            }
        }

        // ---- Lane-local online-softmax partials over 64 rows ----
        float mx = -1e30f;
        #pragma unroll
        for (int m = 0; m < 4; ++m)
            #pragma unroll
            for (int ii = 0; ii < 4; ++ii) {
                int s = t0 + m * 16 + hi4 * 4 + ii;
                if (s <= SDIM) mx = fmaxf(mx, p2[m][0][ii]);
            }
        float se = 0.f, st = 0.f;
        #pragma unroll
        for (int m = 0; m < 4; ++m)
            #pragma unroll
            for (int ii = 0; ii < 4; ++ii) {
                int s = t0 + m * 16 + hi4 * 4 + ii;
                if (s <= SDIM) {
                    float e = __expf(p2[m][0][ii] - mx);
                    se += e;
                    st += e * p2[m][1][ii];
                }
            }
        #pragma unroll
        for (int d = 16; d <= 32; d <<= 1) {
            float mo  = __shfl_xor(mx, d);
            float seo = __shfl_xor(se, d);
            float sto = __shfl_xor(st, d);
            float M  = fmaxf(mx, mo);
            float w0 = __expf(mx - M), w1 = __expf(mo - M);
            se = se * w0 + seo * w1;
            st = st * w0 + sto * w1;
            mx = M;
        }
        if (lane < 16) {
            int l = wid * 16 + l15;
            if (l < LDIM) {
                size_t o = (((size_t)b * NTT + (tbeg + i)) * LDIM + l) * 3;
                part[o] = mx; part[o + 1] = se; part[o + 2] = st;
            }
        }
        __syncthreads();   // tile boundary: next-tile buffer safe to fill/read
    }
}

// ---- Merge NTT tile partials -> logits ----
__global__ void final_kernel(const float* __restrict__ part, const float* __restrict__ final_b,
                             float* __restrict__ out)
{
    int b = blockIdx.x, l = threadIdx.x;
    if (l >= LDIM) return;
    float mx = -1e30f, se = 0.f, st = 0.f;
    for (int c = 0; c < NTT; ++c) {
        size_t o = (((size_t)b * NTT + c) * LDIM + l) * 3;
        float mo = part[o], seo = part[o + 1], sto = part[o + 2];
        float M  = fmaxf(mx, mo);
        float w0 = __expf(mx - M), w1 = __expf(mo - M);
        se = se * w0 + seo * w1;
        st = st * w0 + sto * w1;
        mx = M;
    }
    out[b * LDIM + l] = st / se + final_b[l];
}

extern "C" void kernel_launch(void* const* d_in, const int* in_sizes, int n_in,
                              void* d_out, int out_size, void* d_ws, size_t ws_size,
                              hipStream_t stream)
{
    const int*   ids     = (const int*)d_in[0];
    const float* emb     = (const float*)d_in[1];
    const float* conv_w  = (const float*)d_in[2];
    const float* conv_b  = (const float*)d_in[3];
    const float* U_w     = (const float*)d_in[4];
    const float* final_w = (const float*)d_in[5];
    const float* final_b = (const float*)d_in[6];

    char* ws = (char*)d_ws;
    size_t offE  = 0;
    size_t szE   = (size_t)30522 * 256 * 2;
    size_t offWb = offE + szE;
    size_t szWb  = 256 * 1024 * 2;
    size_t offW2 = offWb + szWb;
    size_t szW2  = 32768 * 2;
    size_t offZ  = offW2 + szW2;
    size_t szZ   = 512;
    size_t offP  = offZ + szZ;   // 32*65*50*3 fp32 = 1,248,000 B

    unsigned short* embb = (unsigned short*)(ws + offE);
    unsigned short* Wb   = (unsigned short*)(ws + offWb);
    unsigned short* W2k  = (unsigned short*)(ws + offW2);
    uint32_t*       zp   = (uint32_t*)(ws + offZ);
    float*          prt  = (float*)(ws + offP);

    prep_misc<<<1024, 256, 0, stream>>>(conv_w, U_w, final_w, Wb, W2k, zp);
    prep_embb<<<3816, 256, 0, stream>>>(emb, embb);
    fused_kernel<<<dim3(NCH, BDIM), 256, 0, stream>>>(ids, embb, Wb, conv_b, W2k, zp, prt);
    final_kernel<<<BDIM, 64, 0, stream>>>(prt, final_b, (float*)d_out);
}

// Round 6
// 105.610 us; speedup vs baseline: 3.4805x; 3.4805x over previous
//
#include <hip/hip_runtime.h>
#include <hip/hip_bf16.h>
#include <stdint.h>

#define BDIM 32
#define SDIM 4096
#define SP1  4097
#define EDIM 256
#define FDIM 256
#define LDIM 50
#define TTILE 96
#define NT    43   // ceil(4097/96)

typedef __attribute__((ext_vector_type(8))) short bf16x8v;
typedef __attribute__((ext_vector_type(4))) float f32x4;

__device__ __forceinline__ unsigned short f2bf(float f) {
    union { float f; uint32_t u; } v; v.f = f;
    uint32_t u = v.u;
    uint32_t r = (u + 0x7fffu + ((u >> 16) & 1u)) >> 16;
    return (unsigned short)r;
}

// tanh(x) = 1 - 2/(1+e^{2x}); v_rcp_f32 (~1ulp) is plenty vs bf16 storage noise.
__device__ __forceinline__ float tanh_fast(float x) {
    float e = __expf(2.0f * x);
    float r = __builtin_amdgcn_rcpf(e + 1.0f);
    return fmaf(-2.0f, r, 1.0f);
}

__device__ __forceinline__ uint32_t pack_bf2(float lo, float hi) {
    union { __hip_bfloat162 v; uint32_t u; } cv;
    cv.v = __halves2bfloat162(__float2bfloat16(lo), __float2bfloat16(hi));
    return cv.u;
}

__device__ __forceinline__ void load_lds16(const void* g, uint32_t* l) {
    __builtin_amdgcn_global_load_lds(
        (const __attribute__((address_space(1))) uint32_t*)g,
        (__attribute__((address_space(3))) uint32_t*)l, 16, 0, 0);
}

// ---- Prep A: Wb2[g][hi4][f][8] bf16 (g=k*8+es), W2k[g][c][j] bf16, zero page ----
__global__ void prep_misc(const float* __restrict__ conv_w,
                          const float* __restrict__ U_w, const float* __restrict__ final_w,
                          unsigned short* __restrict__ Wb2, unsigned short* __restrict__ W2k,
                          uint32_t* __restrict__ zp) {
    int o = blockIdx.x * 256 + threadIdx.x;          // grid 1024 -> o < 262144
    {
        int kk = o & 1023, f = o >> 10;
        int e = kk & 255, k = kk >> 8;
        int g = kk >> 5, h4 = (kk >> 3) & 3, j = kk & 7;
        Wb2[((size_t)(g * 4 + h4) * 256 + f) * 8 + j] = f2bf(conv_w[f * 1024 + e * 4 + k]);
    }
    if (o < 32768) {
        int j = o & 7, c = (o >> 3) & 127, g = o >> 10;
        int k = g * 8 + j, l = c & 63;
        float v = 0.f;
        if (l < LDIM) v = (c < 64) ? U_w[l * FDIM + k] : final_w[l * FDIM + k];
        W2k[o] = f2bf(v);
    }
    if (o < 128) zp[o] = 0;
}

// ---- Prep B: embedding table fp32 -> bf16 ----
__global__ void prep_embb(const float* __restrict__ emb, unsigned short* __restrict__ embb) {
    size_t o = ((size_t)blockIdx.x * 256 + threadIdx.x) * 8;
    if (o >= (size_t)30522 * 256) return;
    float4 v0 = *(const float4*)(emb + o);
    float4 v1 = *(const float4*)(emb + o + 4);
    union { unsigned short u[8]; uint4 q; } pk;
    pk.u[0] = f2bf(v0.x); pk.u[1] = f2bf(v0.y); pk.u[2] = f2bf(v0.z); pk.u[3] = f2bf(v0.w);
    pk.u[4] = f2bf(v1.x); pk.u[5] = f2bf(v1.y); pk.u[6] = f2bf(v1.z); pk.u[7] = f2bf(v1.w);
    *(uint4*)(embb + o) = pk.q;
}

// ---- Fused: gather -> conv1d+tanh (LDS H-tile) -> scores|t GEMM -> softmax partials ----
__global__ __launch_bounds__(256, 2) void fused_kernel(
    const int* __restrict__ ids, const unsigned short* __restrict__ embb,
    const unsigned short* __restrict__ Wb2, const float* __restrict__ conv_b,
    const unsigned short* __restrict__ W2k, const uint32_t* __restrict__ zp,
    float* __restrict__ part)
{
    __shared__ uint32_t xs[100 * 128];   // 51,200 B: x-tile rows 0..99, reused as H-tile

    const int tid  = threadIdx.x;
    const int lane = tid & 63;
    const int wid  = tid >> 6;
    const int b    = blockIdx.y;
    const int tile = blockIdx.x;
    const int t0   = tile * TTILE;
    const int l15  = lane & 15;
    const int hi4  = lane >> 4;
    const int q    = lane & 31;
    const int half = lane >> 5;

    // ---- stage: load all 13 ids first (one latency bubble), then issue all gathers ----
    {
        int nid[13];
        #pragma unroll
        for (int j = 0; j < 13; ++j) {
            int r0 = wid * 2 + j * 8;
            int r  = r0 + half;
            int p  = t0 - 2 + r;
            nid[j] = -1;
            if (r0 < 100 && r < 99 && (unsigned)p < SDIM)
                nid[j] = ids[b * SDIM + p];
        }
        const unsigned short* zs = (const unsigned short*)zp + q * 8;
        const uint32_t soff = ((uint32_t)(q * 16) ^ ((uint32_t)((wid * 2 + half) & 7) << 4)) >> 1;
        #pragma unroll
        for (int j = 0; j < 13; ++j) {
            int r0 = wid * 2 + j * 8;
            if (r0 >= 100) continue;                     // wave-uniform guard
            int r = r0 + half;
            const unsigned short* s = (nid[j] >= 0)
                ? embb + (size_t)nid[j] * EDIM + (((uint32_t)(q * 16) ^ ((uint32_t)(r & 7) << 4)) >> 1)
                : zs;
            load_lds16(s, &xs[r0 * 128]);
        }
        (void)soff;
    }
    __syncthreads();

    // ---- Conv GEMM: wave = 64 filters (M) x 96 positions (N), K=1024 ----
    // Weights streamed from Wb2 [g][hi4][f][8]: per-lane base + g*16KB + a*256B.
    const int fbase = wid * 64;
    const unsigned short* afbase = Wb2 + (size_t)(hi4 * 256 + fbase + l15) * 8;

    f32x4 acc[4][6];
    #pragma unroll
    for (int a = 0; a < 4; ++a)
        #pragma unroll
        for (int n = 0; n < 6; ++n) acc[a][n] = (f32x4){0.f, 0.f, 0.f, 0.f};

    bf16x8v afc[4];
    #pragma unroll
    for (int a = 0; a < 4; ++a) afc[a] = *(const bf16x8v*)(afbase + a * 128);   // g=0

    #pragma unroll 1
    for (int k = 0; k < 4; ++k) {
        uint32_t bb[6];
        #pragma unroll
        for (int n = 0; n < 6; ++n) {
            int r = n * 16 + l15 + k;
            bb[n] = (uint32_t)(r * 512) ^ (uint32_t)(hi4 * 16) ^ (uint32_t)((r & 7) << 4);
        }
        const unsigned short* afg = afbase + (size_t)k * 65536;
        #pragma unroll
        for (int es = 0; es < 8; ++es) {
            // prefetch next g's A-fragments (always 4 loads in flight)
            const unsigned short* nxt = (es < 7)
                ? (afg + (size_t)(es + 1) * 8192)
                : (afbase + (size_t)((k + 1) & 3) * 65536);
            bf16x8v afn[4];
            #pragma unroll
            for (int a = 0; a < 4; ++a) afn[a] = *(const bf16x8v*)(nxt + a * 128);

            bf16x8v bfr[6];
            #pragma unroll
            for (int n = 0; n < 6; ++n)
                bfr[n] = *(const bf16x8v*)((const char*)xs + (bb[n] ^ (uint32_t)(es * 64)));

            __builtin_amdgcn_s_setprio(1);
            #pragma unroll
            for (int a = 0; a < 4; ++a)
                #pragma unroll
                for (int n = 0; n < 6; ++n)
                    acc[a][n] = __builtin_amdgcn_mfma_f32_16x16x32_bf16(afc[a], bfr[n], acc[a][n], 0, 0, 0);
            __builtin_amdgcn_s_setprio(0);

            #pragma unroll
            for (int a = 0; a < 4; ++a) afc[a] = afn[a];
        }
    }
    __syncthreads();   // all waves done reading xs

    // ---- tanh epilogue -> H-tile into LDS (same buffer), XOR-swizzled ----
    float4 cb[4];
    #pragma unroll
    for (int a = 0; a < 4; ++a)
        cb[a] = *(const float4*)(conv_b + fbase + a * 16 + hi4 * 4);
    #pragma unroll
    for (int n = 0; n < 6; ++n) {
        int tl = n * 16 + l15;
        uint32_t hb = (uint32_t)(tl * 512) ^ (uint32_t)(hi4 * 8)
                    ^ (uint32_t)(fbase * 2) ^ (uint32_t)((tl & 7) << 4);
        #pragma unroll
        for (int a = 0; a < 4; ++a) {
            f32x4 d = acc[a][n];
            uint2 pk;
            pk.x = pack_bf2(tanh_fast(d[0] + cb[a].x), tanh_fast(d[1] + cb[a].y));
            pk.y = pack_bf2(tanh_fast(d[2] + cb[a].z), tanh_fast(d[3] + cb[a].w));
            *(uint2*)((char*)xs + (hb ^ (uint32_t)(a * 32))) = pk;
        }
    }
    __syncthreads();

    // ---- P GEMM: 96 s-rows x 32 cols per wave (cbase..+15 scores, +64 t), K=256 ----
    const int cbase = wid * 16;
    f32x4 p2[6][2];
    #pragma unroll
    for (int m = 0; m < 6; ++m) { p2[m][0] = (f32x4){0,0,0,0}; p2[m][1] = (f32x4){0,0,0,0}; }

    uint32_t pb[6];
    #pragma unroll
    for (int m = 0; m < 6; ++m) {
        int sl = m * 16 + l15;
        pb[m] = (uint32_t)(sl * 512) ^ (uint32_t)(hi4 * 16) ^ (uint32_t)((sl & 7) << 4);
    }
    const unsigned short* wp0 = W2k + (size_t)(hi4 * 128 + cbase + l15) * 8;

    #pragma unroll
    for (int step = 0; step < 8; ++step) {
        bf16x8v ha[6], w2[2];
        #pragma unroll
        for (int m = 0; m < 6; ++m)
            ha[m] = *(const bf16x8v*)((const char*)xs + (pb[m] ^ (uint32_t)(step * 64)));
        w2[0] = *(const bf16x8v*)(wp0 + step * 4096);
        w2[1] = *(const bf16x8v*)(wp0 + 512 + step * 4096);
        __builtin_amdgcn_s_setprio(1);
        #pragma unroll
        for (int m = 0; m < 6; ++m) {
            p2[m][0] = __builtin_amdgcn_mfma_f32_16x16x32_bf16(ha[m], w2[0], p2[m][0], 0, 0, 0);
            p2[m][1] = __builtin_amdgcn_mfma_f32_16x16x32_bf16(ha[m], w2[1], p2[m][1], 0, 0, 0);
        }
        __builtin_amdgcn_s_setprio(0);
    }

    // ---- Lane-local online-softmax partials ----
    float mx = -1e30f;
    #pragma unroll
    for (int m = 0; m < 6; ++m)
        #pragma unroll
        for (int i = 0; i < 4; ++i) {
            int s = t0 + m * 16 + hi4 * 4 + i;
            if (s <= SDIM) mx = fmaxf(mx, p2[m][0][i]);
        }
    float se = 0.f, st = 0.f;
    #pragma unroll
    for (int m = 0; m < 6; ++m)
        #pragma unroll
        for (int i = 0; i < 4; ++i) {
            int s = t0 + m * 16 + hi4 * 4 + i;
            if (s <= SDIM) {
                float e = __expf(p2[m][0][i] - mx);
                se += e;
                st += e * p2[m][1][i];
            }
        }
    #pragma unroll
    for (int d = 16; d <= 32; d <<= 1) {
        float mo  = __shfl_xor(mx, d);
        float seo = __shfl_xor(se, d);
        float sto = __shfl_xor(st, d);
        float M  = fmaxf(mx, mo);
        float w0 = __expf(mx - M), w1 = __expf(mo - M);
        se = se * w0 + seo * w1;
        st = st * w0 + sto * w1;
        mx = M;
    }
    if (lane < 16) {
        int l = cbase + l15;
        if (l < LDIM) {
            size_t o = (((size_t)b * NT + tile) * LDIM + l) * 3;
            part[o] = mx; part[o + 1] = se; part[o + 2] = st;
        }
    }
}

// ---- Merge NT tile partials -> logits ----
__global__ void final_kernel(const float* __restrict__ part, const float* __restrict__ final_b,
                             float* __restrict__ out)
{
    int b = blockIdx.x, l = threadIdx.x;
    if (l >= LDIM) return;
    float mx = -1e30f, se = 0.f, st = 0.f;
    for (int c = 0; c < NT; ++c) {
        size_t o = (((size_t)b * NT + c) * LDIM + l) * 3;
        float mo = part[o], seo = part[o + 1], sto = part[o + 2];
        float M  = fmaxf(mx, mo);
        float w0 = __expf(mx - M), w1 = __expf(mo - M);
        se = se * w0 + seo * w1;
        st = st * w0 + sto * w1;
        mx = M;
    }
    out[b * LDIM + l] = st / se + final_b[l];
}

extern "C" void kernel_launch(void* const* d_in, const int* in_sizes, int n_in,
                              void* d_out, int out_size, void* d_ws, size_t ws_size,
                              hipStream_t stream)
{
    const int*   ids     = (const int*)d_in[0];
    const float* emb     = (const float*)d_in[1];
    const float* conv_w  = (const float*)d_in[2];
    const float* conv_b  = (const float*)d_in[3];
    const float* U_w     = (const float*)d_in[4];
    const float* final_w = (const float*)d_in[5];
    const float* final_b = (const float*)d_in[6];

    char* ws = (char*)d_ws;
    size_t offE  = 0;
    size_t szE   = (size_t)30522 * 256 * 2;
    size_t offWb = offE + szE;
    size_t szWb  = 256 * 1024 * 2;
    size_t offW2 = offWb + szWb;
    size_t szW2  = 32768 * 2;
    size_t offZ  = offW2 + szW2;
    size_t szZ   = 512;
    size_t offP  = offZ + szZ;

    unsigned short* embb = (unsigned short*)(ws + offE);
    unsigned short* Wb2  = (unsigned short*)(ws + offWb);
    unsigned short* W2k  = (unsigned short*)(ws + offW2);
    uint32_t*       zp   = (uint32_t*)(ws + offZ);
    float*          prt  = (float*)(ws + offP);

    prep_misc<<<1024, 256, 0, stream>>>(conv_w, U_w, final_w, Wb2, W2k, zp);
    prep_embb<<<3816, 256, 0, stream>>>(emb, embb);
    fused_kernel<<<dim3(NT, BDIM), 256, 0, stream>>>(ids, embb, Wb2, conv_b, W2k, zp, prt);
    final_kernel<<<BDIM, 64, 0, stream>>>(prt, final_b, (float*)d_out);
}